// Round 1
// baseline (8873.769 us; speedup 1.0000x reference)
//
#include <hip/hip_runtime.h>
#include <hip/hip_bf16.h>

#define SEQ 2048
#define BATCH 16
#define HID 512
#define OUT_DIM 10
#define NLAYERS 5
#define M_ROWS (SEQ * BATCH)   // 32768
#define N3H (3 * HID)          // 1536

// ---------------- GEMM: U[m][g] = sum_k A[m][k] * W[g][k] ----------------
// A: [M][512] f32 (row-major, K-contiguous), W: [1536][512] f32 (K-contiguous)
// 128x128 tile, BK=32, 256 threads, 8x8 accumulator per thread.
#define BM 128
#define BN 128
#define BK 32
#define LPAD 4

__global__ __launch_bounds__(256) void gemm_nt(const float* __restrict__ A,
                                               const float* __restrict__ B,
                                               float* __restrict__ C) {
  __shared__ float As[BK][BM + LPAD];
  __shared__ float Bs[BK][BN + LPAD];
  const int K = HID;
  const int N = N3H;
  const int bm = blockIdx.x;
  const int bn = blockIdx.y;
  const int tid = threadIdx.x;
  const int tn = tid & 15;   // N sub-block (consecutive lanes -> consecutive cols: coalesced C writes)
  const int tm = tid >> 4;   // M sub-block

  float acc[8][8];
#pragma unroll
  for (int i = 0; i < 8; ++i)
#pragma unroll
    for (int j = 0; j < 8; ++j) acc[i][j] = 0.f;

  const float* Ab = A + (size_t)bm * BM * K;
  const float* Bb = B + (size_t)bn * BN * K;

  for (int k0 = 0; k0 < K; k0 += BK) {
    // stage A,B tiles: 128 rows x 32 floats = 1024 float4 each; 4 float4/thread
#pragma unroll
    for (int i = 0; i < 4; ++i) {
      int f = tid + i * 256;     // 0..1023
      int row = f >> 3;          // 0..127
      int kq = f & 7;            // float4 index within the 32-float row chunk
      float4 av = *(const float4*)(Ab + (size_t)row * K + k0 + kq * 4);
      As[kq * 4 + 0][row] = av.x;
      As[kq * 4 + 1][row] = av.y;
      As[kq * 4 + 2][row] = av.z;
      As[kq * 4 + 3][row] = av.w;
      float4 bv = *(const float4*)(Bb + (size_t)row * K + k0 + kq * 4);
      Bs[kq * 4 + 0][row] = bv.x;
      Bs[kq * 4 + 1][row] = bv.y;
      Bs[kq * 4 + 2][row] = bv.z;
      Bs[kq * 4 + 3][row] = bv.w;
    }
    __syncthreads();

#pragma unroll 4
    for (int k = 0; k < BK; ++k) {
      float a[8], b[8];
      *(float4*)&a[0] = *(const float4*)&As[k][tm * 8];
      *(float4*)&a[4] = *(const float4*)&As[k][tm * 8 + 4];
      *(float4*)&b[0] = *(const float4*)&Bs[k][tn * 8];
      *(float4*)&b[4] = *(const float4*)&Bs[k][tn * 8 + 4];
#pragma unroll
      for (int i = 0; i < 8; ++i)
#pragma unroll
        for (int j = 0; j < 8; ++j) acc[i][j] += a[i] * b[j];
    }
    __syncthreads();
  }

  // write C (coalesced: consecutive lanes cover consecutive 8-col groups)
  float* Cb = C + (size_t)(bm * BM + tm * 8) * N + bn * BN + tn * 8;
#pragma unroll
  for (int i = 0; i < 8; ++i) {
    float4 v0 = {acc[i][0], acc[i][1], acc[i][2], acc[i][3]};
    float4 v1 = {acc[i][4], acc[i][5], acc[i][6], acc[i][7]};
    *(float4*)(Cb + (size_t)i * N) = v0;
    *(float4*)(Cb + (size_t)i * N + 4) = v1;
  }
}

// ---------------- SRU scan: gates + recurrence + highway ----------------
// U: [L][B][3H] = [xt | zf | zr]; xin: [L][B][H]; hout: [L][B][H]
// One thread per (b,h): 8192 threads. hout may alias xin (same-thread
// read-before-write per element).
__global__ __launch_bounds__(256) void sru_scan(const float* __restrict__ U,
                                                const float* __restrict__ xin,
                                                const float* __restrict__ bias,  // [2H]
                                                float* __restrict__ hout) {
  int t = blockIdx.x * 256 + threadIdx.x;  // 0..8191
  int b = t >> 9;
  int h = t & 511;
  const float bf = bias[h];
  const float br = bias[HID + h];
  const float* Urow = U + (size_t)b * N3H + h;
  const float* xrow = xin + (size_t)b * HID + h;
  float* hrow = hout + (size_t)b * HID + h;
  float c = 0.f;
#pragma unroll 8
  for (int l = 0; l < SEQ; ++l) {
    size_t uo = (size_t)l * BATCH * N3H;
    size_t xo = (size_t)l * BATCH * HID;
    float xt = Urow[uo];
    float zf = Urow[uo + HID];
    float zr = Urow[uo + 2 * HID];
    float xv = xrow[xo];
    float f = 1.f / (1.f + __expf(-(zf + bf)));
    float r = 1.f / (1.f + __expf(-(zr + br)));
    c = f * c + (1.f - f) * xt;
    hrow[xo] = r * c + (1.f - r) * xv;
  }
}

// ---------------- FC head: out[m][o] = sum_h H[m][h]*W[o][h] + b[o] ----------------
#define FCR 16
__global__ __launch_bounds__(256) void fc_kernel(const float* __restrict__ H,
                                                 const float* __restrict__ W,   // [10][512]
                                                 const float* __restrict__ bv,  // [10]
                                                 float* __restrict__ out) {
  __shared__ float hs[FCR][516];
  __shared__ float ws[OUT_DIM][516];
  const int tid = threadIdx.x;
  const size_t m0 = (size_t)blockIdx.x * FCR;
  // load 16 rows of H: 2048 float4 -> 8/thread
#pragma unroll
  for (int i = 0; i < 8; ++i) {
    int f = tid + i * 256;
    int row = f >> 7;    // 0..15
    int kq = f & 127;    // float4 within row
    float4 v = *(const float4*)(H + (m0 + row) * 512 + kq * 4);
    *(float4*)&hs[row][kq * 4] = v;
  }
  // load W: 1280 float4 -> 5/thread
#pragma unroll
  for (int i = 0; i < 5; ++i) {
    int f = tid + i * 256;
    int row = f >> 7;    // 0..9
    int kq = f & 127;
    float4 v = *(const float4*)(W + row * 512 + kq * 4);
    *(float4*)&ws[row][kq * 4] = v;
  }
  __syncthreads();
  if (tid < FCR * OUT_DIM) {
    int row = tid / OUT_DIM;
    int o = tid - row * OUT_DIM;
    float acc = bv[o];
#pragma unroll 8
    for (int k = 0; k < 512; ++k) acc += hs[row][k] * ws[o][k];
    out[(m0 + row) * OUT_DIM + o] = acc;
  }
}

extern "C" void kernel_launch(void* const* d_in, const int* in_sizes, int n_in,
                              void* d_out, int out_size, void* d_ws, size_t ws_size,
                              hipStream_t stream) {
  const float* x   = (const float*)d_in[0];  // [2048][16][512]
  const float* Ws  = (const float*)d_in[1];  // [5][1536][512]
  const float* bs  = (const float*)d_in[2];  // [5][1024]
  const float* fcW = (const float*)d_in[3];  // [10][512]
  const float* fcb = (const float*)d_in[4];  // [10]
  float* out = (float*)d_out;

  char* ws = (char*)d_ws;
  float* U  = (float*)ws;                                      // 192 MiB
  float* hA = (float*)(ws + (size_t)M_ROWS * N3H * 4);         // 64 MiB
  // total ws need: 256 MiB

  const float* hin = x;
  for (int l = 0; l < NLAYERS; ++l) {
    dim3 g(M_ROWS / BM, N3H / BN);
    gemm_nt<<<g, 256, 0, stream>>>(hin, Ws + (size_t)l * N3H * HID, U);
    // layer 0 writes hA (must not mutate input x); layers >=1 scan in place
    float* hout = hA;
    sru_scan<<<32, 256, 0, stream>>>(U, hin, bs + (size_t)l * 2 * HID, hout);
    hin = hout;
  }
  fc_kernel<<<M_ROWS / FCR, 256, 0, stream>>>(hin, fcW, fcb, out);
}

// Round 2
// 8850.608 us; speedup vs baseline: 1.0026x; 1.0026x over previous
//
#include <hip/hip_runtime.h>
#include <hip/hip_bf16.h>

#define SEQ 2048
#define BATCH 16
#define HID 512
#define OUT_DIM 10
#define NLAYERS 5
#define M_ROWS (SEQ * BATCH)   // 32768
#define N3H (3 * HID)          // 1536

#define CHUNK 32
#define NSEG (SEQ / CHUNK)     // 64

// ---------------- GEMM: U[m][g] = sum_k A[m][k] * W[g][k] ----------------
#define BM 128
#define BN 128
#define BK 32
#define LPAD 4

__global__ __launch_bounds__(256) void gemm_nt(const float* __restrict__ A,
                                               const float* __restrict__ B,
                                               float* __restrict__ C) {
  __shared__ float As[BK][BM + LPAD];
  __shared__ float Bs[BK][BN + LPAD];
  const int K = HID;
  const int N = N3H;
  const int bm = blockIdx.x;
  const int bn = blockIdx.y;
  const int tid = threadIdx.x;
  const int tn = tid & 15;
  const int tm = tid >> 4;

  float acc[8][8];
#pragma unroll
  for (int i = 0; i < 8; ++i)
#pragma unroll
    for (int j = 0; j < 8; ++j) acc[i][j] = 0.f;

  const float* Ab = A + (size_t)bm * BM * K;
  const float* Bb = B + (size_t)bn * BN * K;

  for (int k0 = 0; k0 < K; k0 += BK) {
#pragma unroll
    for (int i = 0; i < 4; ++i) {
      int f = tid + i * 256;
      int row = f >> 3;
      int kq = f & 7;
      float4 av = *(const float4*)(Ab + (size_t)row * K + k0 + kq * 4);
      As[kq * 4 + 0][row] = av.x;
      As[kq * 4 + 1][row] = av.y;
      As[kq * 4 + 2][row] = av.z;
      As[kq * 4 + 3][row] = av.w;
      float4 bv = *(const float4*)(Bb + (size_t)row * K + k0 + kq * 4);
      Bs[kq * 4 + 0][row] = bv.x;
      Bs[kq * 4 + 1][row] = bv.y;
      Bs[kq * 4 + 2][row] = bv.z;
      Bs[kq * 4 + 3][row] = bv.w;
    }
    __syncthreads();

#pragma unroll 4
    for (int k = 0; k < BK; ++k) {
      float a[8], b[8];
      *(float4*)&a[0] = *(const float4*)&As[k][tm * 8];
      *(float4*)&a[4] = *(const float4*)&As[k][tm * 8 + 4];
      *(float4*)&b[0] = *(const float4*)&Bs[k][tn * 8];
      *(float4*)&b[4] = *(const float4*)&Bs[k][tn * 8 + 4];
#pragma unroll
      for (int i = 0; i < 8; ++i)
#pragma unroll
        for (int j = 0; j < 8; ++j) acc[i][j] += a[i] * b[j];
    }
    __syncthreads();
  }

  float* Cb = C + (size_t)(bm * BM + tm * 8) * N + bn * BN + tn * 8;
#pragma unroll
  for (int i = 0; i < 8; ++i) {
    float4 v0 = {acc[i][0], acc[i][1], acc[i][2], acc[i][3]};
    float4 v1 = {acc[i][4], acc[i][5], acc[i][6], acc[i][7]};
    *(float4*)(Cb + (size_t)i * N) = v0;
    *(float4*)(Cb + (size_t)i * N + 4) = v1;
  }
}

// ---------------- Segment-parallel SRU scan ----------------
// pass1: per (chain=(b,h), segment s): local (F=prod f, C=c_end | c0=0)
__global__ __launch_bounds__(256) void scan_pass1(const float* __restrict__ U,
                                                  const float* __restrict__ bias,
                                                  float* __restrict__ Fseg,
                                                  float* __restrict__ Cseg) {
  int t = blockIdx.x * 256 + threadIdx.x;   // 0 .. 8192*NSEG-1
  int h = t & (HID - 1);
  int b = (t >> 9) & (BATCH - 1);
  int s = t >> 13;
  const float bf = bias[h];
  const float* Up = U + (size_t)(s * CHUNK) * BATCH * N3H + (size_t)b * N3H + h;
  float F = 1.f, c = 0.f;
#pragma unroll 8
  for (int i = 0; i < CHUNK; ++i) {
    float xt = Up[0];
    float zf = Up[HID];
    float f = 1.f / (1.f + __expf(-(zf + bf)));
    c = f * c + (1.f - f) * xt;
    F *= f;
    Up += BATCH * N3H;
  }
  size_t o = ((size_t)s * BATCH + b) * HID + h;
  Fseg[o] = F;
  Cseg[o] = c;
}

// mid: per chain, serial scan over NSEG segment summaries -> incoming carry
__global__ __launch_bounds__(256) void scan_mid(const float* __restrict__ Fseg,
                                                const float* __restrict__ Cseg,
                                                float* __restrict__ Cin) {
  int t = blockIdx.x * 256 + threadIdx.x;   // 0..8191, t = b*HID + h
  float c = 0.f;
#pragma unroll 4
  for (int s = 0; s < NSEG; ++s) {
    size_t o = (size_t)s * BATCH * HID + t;
    Cin[o] = c;
    c = Fseg[o] * c + Cseg[o];
  }
}

// pass3: apply carry, recompute gates, emit h (hout may alias xin)
__global__ __launch_bounds__(256) void scan_pass3(const float* __restrict__ U,
                                                  const float* __restrict__ xin,
                                                  const float* __restrict__ bias,
                                                  const float* __restrict__ Cin,
                                                  float* __restrict__ hout) {
  int t = blockIdx.x * 256 + threadIdx.x;
  int h = t & (HID - 1);
  int b = (t >> 9) & (BATCH - 1);
  int s = t >> 13;
  const float bf = bias[h];
  const float br = bias[HID + h];
  float c = Cin[(size_t)s * BATCH * HID + (b << 9) + h];
  const float* Up = U + (size_t)(s * CHUNK) * BATCH * N3H + (size_t)b * N3H + h;
  const float* xp = xin + (size_t)(s * CHUNK) * BATCH * HID + (b << 9) + h;
  float* hp = hout + (size_t)(s * CHUNK) * BATCH * HID + (b << 9) + h;
#pragma unroll 4
  for (int i = 0; i < CHUNK; ++i) {
    float xt = Up[0];
    float zf = Up[HID];
    float zr = Up[2 * HID];
    float xv = xp[0];
    float f = 1.f / (1.f + __expf(-(zf + bf)));
    float r = 1.f / (1.f + __expf(-(zr + br)));
    c = f * c + (1.f - f) * xt;
    hp[0] = r * c + (1.f - r) * xv;
    Up += BATCH * N3H;
    xp += BATCH * HID;
    hp += BATCH * HID;
  }
}

// fallback serial scan (used only if workspace is too small for seg buffers)
__global__ __launch_bounds__(256) void sru_scan(const float* __restrict__ U,
                                                const float* __restrict__ xin,
                                                const float* __restrict__ bias,
                                                float* __restrict__ hout) {
  int t = blockIdx.x * 256 + threadIdx.x;
  int b = t >> 9;
  int h = t & 511;
  const float bf = bias[h];
  const float br = bias[HID + h];
  const float* Urow = U + (size_t)b * N3H + h;
  const float* xrow = xin + (size_t)b * HID + h;
  float* hrow = hout + (size_t)b * HID + h;
  float c = 0.f;
#pragma unroll 8
  for (int l = 0; l < SEQ; ++l) {
    size_t uo = (size_t)l * BATCH * N3H;
    size_t xo = (size_t)l * BATCH * HID;
    float xt = Urow[uo];
    float zf = Urow[uo + HID];
    float zr = Urow[uo + 2 * HID];
    float xv = xrow[xo];
    float f = 1.f / (1.f + __expf(-(zf + bf)));
    float r = 1.f / (1.f + __expf(-(zr + br)));
    c = f * c + (1.f - f) * xt;
    hrow[xo] = r * c + (1.f - r) * xv;
  }
}

// ---------------- FC head ----------------
#define FCR 16
__global__ __launch_bounds__(256) void fc_kernel(const float* __restrict__ H,
                                                 const float* __restrict__ W,
                                                 const float* __restrict__ bv,
                                                 float* __restrict__ out) {
  __shared__ float hs[FCR][516];
  __shared__ float ws[OUT_DIM][516];
  const int tid = threadIdx.x;
  const size_t m0 = (size_t)blockIdx.x * FCR;
#pragma unroll
  for (int i = 0; i < 8; ++i) {
    int f = tid + i * 256;
    int row = f >> 7;
    int kq = f & 127;
    float4 v = *(const float4*)(H + (m0 + row) * 512 + kq * 4);
    *(float4*)&hs[row][kq * 4] = v;
  }
#pragma unroll
  for (int i = 0; i < 5; ++i) {
    int f = tid + i * 256;
    int row = f >> 7;
    int kq = f & 127;
    float4 v = *(const float4*)(W + row * 512 + kq * 4);
    *(float4*)&ws[row][kq * 4] = v;
  }
  __syncthreads();
  if (tid < FCR * OUT_DIM) {
    int row = tid / OUT_DIM;
    int o = tid - row * OUT_DIM;
    float acc = bv[o];
#pragma unroll 8
    for (int k = 0; k < 512; ++k) acc += hs[row][k] * ws[o][k];
    out[(m0 + row) * OUT_DIM + o] = acc;
  }
}

extern "C" void kernel_launch(void* const* d_in, const int* in_sizes, int n_in,
                              void* d_out, int out_size, void* d_ws, size_t ws_size,
                              hipStream_t stream) {
  const float* x   = (const float*)d_in[0];  // [2048][16][512]
  const float* Ws  = (const float*)d_in[1];  // [5][1536][512]
  const float* bs  = (const float*)d_in[2];  // [5][1024]
  const float* fcW = (const float*)d_in[3];  // [10][512]
  const float* fcb = (const float*)d_in[4];  // [10]
  float* out = (float*)d_out;

  char* ws = (char*)d_ws;
  const size_t U_bytes  = (size_t)M_ROWS * N3H * 4;        // 192 MiB
  const size_t h_bytes  = (size_t)M_ROWS * HID * 4;        // 64 MiB
  const size_t seg_bytes = (size_t)NSEG * BATCH * HID * 4; // 2 MiB

  float* U    = (float*)ws;
  float* hA   = (float*)(ws + U_bytes);
  float* Fseg = (float*)(ws + U_bytes + h_bytes);
  float* Cseg = (float*)(ws + U_bytes + h_bytes + seg_bytes);
  float* Cin  = (float*)(ws + U_bytes + h_bytes + 2 * seg_bytes);
  const bool seg_ok = ws_size >= U_bytes + h_bytes + 3 * seg_bytes;

  const float* hin = x;
  for (int l = 0; l < NLAYERS; ++l) {
    dim3 g(M_ROWS / BM, N3H / BN);
    gemm_nt<<<g, 256, 0, stream>>>(hin, Ws + (size_t)l * N3H * HID, U);
    float* hout = hA;
    const float* bias = bs + (size_t)l * 2 * HID;
    if (seg_ok) {
      int nthreads = BATCH * HID * NSEG;  // 524288
      scan_pass1<<<nthreads / 256, 256, 0, stream>>>(U, bias, Fseg, Cseg);
      scan_mid<<<BATCH * HID / 256, 256, 0, stream>>>(Fseg, Cseg, Cin);
      scan_pass3<<<nthreads / 256, 256, 0, stream>>>(U, hin, bias, Cin, hout);
    } else {
      sru_scan<<<32, 256, 0, stream>>>(U, hin, bias, hout);
    }
    hin = hout;
  }
  fc_kernel<<<M_ROWS / FCR, 256, 0, stream>>>(hin, fcW, fcb, out);
}

// Round 3
// 797.504 us; speedup vs baseline: 11.1269x; 11.0979x over previous
//
#include <hip/hip_runtime.h>
#include <hip/hip_bf16.h>

#define SEQ 2048
#define BATCH 16
#define HID 512
#define OUT_DIM 10
#define NLAYERS 5
#define M_ROWS (SEQ * BATCH)   // 32768
#define N3H (3 * HID)          // 1536
#define GK HID                 // GEMM K

#define CHUNK 32
#define NSEG (SEQ / CHUNK)     // 64

typedef __attribute__((ext_vector_type(8))) short short8;
typedef __attribute__((ext_vector_type(4))) float f32x4;
typedef __attribute__((ext_vector_type(8))) unsigned short u16x8;

__device__ __forceinline__ unsigned short f2bf(float x) {
  unsigned u = __builtin_bit_cast(unsigned, x);
  u += 0x7fffu + ((u >> 16) & 1u);   // RNE
  return (unsigned short)(u >> 16);
}
__device__ __forceinline__ float bf2f(unsigned short v) {
  return __builtin_bit_cast(float, ((unsigned)v) << 16);
}

// ---------------- f32 -> bf16 bulk convert (8 elems/thread) ----------------
__global__ __launch_bounds__(256) void cvt_f32_to_bf16(const float* __restrict__ in,
                                                       unsigned short* __restrict__ out) {
  size_t i = ((size_t)blockIdx.x * 256 + threadIdx.x) * 8;
  float4 a = *(const float4*)(in + i);
  float4 b = *(const float4*)(in + i + 4);
  u16x8 r;
  r[0] = f2bf(a.x); r[1] = f2bf(a.y); r[2] = f2bf(a.z); r[3] = f2bf(a.w);
  r[4] = f2bf(b.x); r[5] = f2bf(b.y); r[6] = f2bf(b.z); r[7] = f2bf(b.w);
  *(u16x8*)(out + i) = r;
}

// ---------------- bf16 MFMA GEMM: C[m][n] = sum_k A[m][k] * B[n][k] ----------------
// A: [M][512] bf16 row-major; B: [1536][512] bf16 (B^T layout); C: [M][1536] bf16.
// 128x128 tile, BK=32, 256 threads (4 waves, each a 64x64 quadrant).
__global__ __launch_bounds__(256) void gemm_mfma(const unsigned short* __restrict__ A,
                                                 const unsigned short* __restrict__ B,
                                                 unsigned short* __restrict__ C) {
  __shared__ unsigned short lds[2][8192];  // [buf]: A tile 128x32 @0, B tile @4096
  const int tid = threadIdx.x;
  const int bm = blockIdx.x, bn = blockIdx.y;
  const int lane = tid & 63;
  const int wid = tid >> 6;
  const int wm = (wid >> 1) * 64, wn = (wid & 1) * 64;

  const unsigned short* Ag = A + (size_t)bm * 128 * GK;
  const unsigned short* Bg = B + (size_t)bn * 128 * GK;

  // staging: slot s in [0,512) covers (row = s>>2, 8-elem chunk = s&3)
  const int s0 = tid, s1 = tid + 256;
  const int r0 = s0 >> 2, c0 = (s0 & 3) * 8;
  const int r1 = s1 >> 2, c1 = (s1 & 3) * 8;

  const int fr = lane & 15;         // fragment row (M for A, N for B)
  const int ko = (lane >> 4) * 8;   // fragment k offset (8 contiguous)

  f32x4 acc[4][4];
#pragma unroll
  for (int i = 0; i < 4; ++i)
#pragma unroll
    for (int j = 0; j < 4; ++j) acc[i][j] = (f32x4){0.f, 0.f, 0.f, 0.f};

#define STAGE(buf, k0)                                                                              \
  {                                                                                                 \
    __builtin_amdgcn_global_load_lds(                                                               \
        (const __attribute__((address_space(1))) void*)(Ag + (size_t)r0 * GK + (k0) + c0),          \
        (__attribute__((address_space(3))) void*)&lds[buf][s0 * 8], 16, 0, 0);                      \
    __builtin_amdgcn_global_load_lds(                                                               \
        (const __attribute__((address_space(1))) void*)(Ag + (size_t)r1 * GK + (k0) + c1),          \
        (__attribute__((address_space(3))) void*)&lds[buf][s1 * 8], 16, 0, 0);                      \
    __builtin_amdgcn_global_load_lds(                                                               \
        (const __attribute__((address_space(1))) void*)(Bg + (size_t)r0 * GK + (k0) + c0),          \
        (__attribute__((address_space(3))) void*)&lds[buf][4096 + s0 * 8], 16, 0, 0);               \
    __builtin_amdgcn_global_load_lds(                                                               \
        (const __attribute__((address_space(1))) void*)(Bg + (size_t)r1 * GK + (k0) + c1),          \
        (__attribute__((address_space(3))) void*)&lds[buf][4096 + s1 * 8], 16, 0, 0);               \
  }

  STAGE(0, 0);
  __syncthreads();
  int cur = 0;
#pragma unroll 1
  for (int kt = 0; kt < GK / 32; ++kt) {
    if (kt + 1 < GK / 32) STAGE(cur ^ 1, (kt + 1) * 32);
    short8 af[4], bfr[4];
#pragma unroll
    for (int t = 0; t < 4; ++t) {
      af[t]  = *(const short8*)&lds[cur][(wm + t * 16 + fr) * 32 + ko];
      bfr[t] = *(const short8*)&lds[cur][4096 + (wn + t * 16 + fr) * 32 + ko];
    }
#pragma unroll
    for (int mt = 0; mt < 4; ++mt)
#pragma unroll
      for (int nt = 0; nt < 4; ++nt)
        acc[mt][nt] = __builtin_amdgcn_mfma_f32_16x16x32_bf16(af[mt], bfr[nt], acc[mt][nt], 0, 0, 0);
    if (kt + 1 < GK / 32) {
      __syncthreads();   // drains vmcnt (stage done) + lgkm (reads done)
      cur ^= 1;
    }
  }
#undef STAGE

  // C/D layout (HW-verified): col = lane&15, row = (lane>>4)*4 + reg
  const int crow0 = bm * 128 + wm + (lane >> 4) * 4;
  const int ccol0 = bn * 128 + wn + fr;
#pragma unroll
  for (int mt = 0; mt < 4; ++mt)
#pragma unroll
    for (int nt = 0; nt < 4; ++nt)
#pragma unroll
      for (int j = 0; j < 4; ++j)
        C[(size_t)(crow0 + mt * 16 + j) * N3H + ccol0 + nt * 16] = f2bf(acc[mt][nt][j]);
}

// ---------------- Segment-parallel SRU scan ----------------
__global__ __launch_bounds__(256) void scan_pass1(const unsigned short* __restrict__ U,
                                                  const float* __restrict__ bias,
                                                  float* __restrict__ Fseg,
                                                  float* __restrict__ Cseg) {
  int t = blockIdx.x * 256 + threadIdx.x;   // (s, b, h)
  int h = t & (HID - 1);
  int b = (t >> 9) & (BATCH - 1);
  int s = t >> 13;
  const float bfv = bias[h];
  const unsigned short* Up = U + (size_t)(s * CHUNK) * BATCH * N3H + (size_t)b * N3H + h;
  float F = 1.f, c = 0.f;
#pragma unroll 8
  for (int i = 0; i < CHUNK; ++i) {
    float xt = bf2f(Up[0]);
    float zf = bf2f(Up[HID]);
    float f = 1.f / (1.f + __expf(-(zf + bfv)));
    c = f * c + (1.f - f) * xt;
    F *= f;
    Up += BATCH * N3H;
  }
  size_t o = ((size_t)s * BATCH + b) * HID + h;
  Fseg[o] = F;
  Cseg[o] = c;
}

// per chain: serial scan over segment summaries; writes the INCOMING carry
// for each segment in-place into Cseg.
__global__ __launch_bounds__(256) void scan_mid(const float* __restrict__ Fseg,
                                                float* Cseg) {
  int t = blockIdx.x * 256 + threadIdx.x;   // 0..8191
  float c = 0.f;
#pragma unroll 4
  for (int s = 0; s < NSEG; ++s) {
    size_t o = (size_t)s * BATCH * HID + t;
    float F = Fseg[o], Cv = Cseg[o];
    Cseg[o] = c;          // incoming carry for segment s
    c = F * c + Cv;
  }
}

// pass3: apply carry, recompute gates, highway; writes f32 h + bf16 mirror.
// xin/hF may alias (in-place): per element read-then-write by same thread.
__global__ __launch_bounds__(256) void scan_pass3(const unsigned short* __restrict__ U,
                                                  const float* xin,
                                                  const float* __restrict__ bias,
                                                  const float* __restrict__ Cin,
                                                  float* hF,
                                                  unsigned short* __restrict__ hB) {
  int t = blockIdx.x * 256 + threadIdx.x;
  int h = t & (HID - 1);
  int b = (t >> 9) & (BATCH - 1);
  int s = t >> 13;
  const float bfv = bias[h];
  const float brv = bias[HID + h];
  float c = Cin[(size_t)s * BATCH * HID + (b << 9) + h];
  const unsigned short* Up = U + (size_t)(s * CHUNK) * BATCH * N3H + (size_t)b * N3H + h;
  const float* xp = xin + (size_t)(s * CHUNK) * BATCH * HID + (b << 9) + h;
  float* hp = hF + (size_t)(s * CHUNK) * BATCH * HID + (b << 9) + h;
  unsigned short* hbp = hB + (size_t)(s * CHUNK) * BATCH * HID + (b << 9) + h;
#pragma unroll 4
  for (int i = 0; i < CHUNK; ++i) {
    float xt = bf2f(Up[0]);
    float zf = bf2f(Up[HID]);
    float zr = bf2f(Up[2 * HID]);
    float xv = xp[0];
    float f = 1.f / (1.f + __expf(-(zf + bfv)));
    float r = 1.f / (1.f + __expf(-(zr + brv)));
    c = f * c + (1.f - f) * xt;
    float hv = r * c + (1.f - r) * xv;
    hp[0] = hv;
    hbp[0] = f2bf(hv);
    Up += BATCH * N3H;
    xp += BATCH * HID;
    hp += BATCH * HID;
    hbp += BATCH * HID;
  }
}

// ---------------- FC head (f32 H) ----------------
#define FCR 16
__global__ __launch_bounds__(256) void fc_kernel(const float* __restrict__ H,
                                                 const float* __restrict__ W,
                                                 const float* __restrict__ bv,
                                                 float* __restrict__ out) {
  __shared__ float hs[FCR][516];
  __shared__ float ws[OUT_DIM][516];
  const int tid = threadIdx.x;
  const size_t m0 = (size_t)blockIdx.x * FCR;
#pragma unroll
  for (int i = 0; i < 8; ++i) {
    int f = tid + i * 256;
    int row = f >> 7;
    int kq = f & 127;
    float4 v = *(const float4*)(H + (m0 + row) * 512 + kq * 4);
    *(float4*)&hs[row][kq * 4] = v;
  }
#pragma unroll
  for (int i = 0; i < 5; ++i) {
    int f = tid + i * 256;
    int row = f >> 7;
    int kq = f & 127;
    float4 v = *(const float4*)(W + row * 512 + kq * 4);
    *(float4*)&ws[row][kq * 4] = v;
  }
  __syncthreads();
  if (tid < FCR * OUT_DIM) {
    int row = tid / OUT_DIM;
    int o = tid - row * OUT_DIM;
    float acc = bv[o];
#pragma unroll 8
    for (int k = 0; k < 512; ++k) acc += hs[row][k] * ws[o][k];
    out[(m0 + row) * OUT_DIM + o] = acc;
  }
}

extern "C" void kernel_launch(void* const* d_in, const int* in_sizes, int n_in,
                              void* d_out, int out_size, void* d_ws, size_t ws_size,
                              hipStream_t stream) {
  const float* x   = (const float*)d_in[0];  // [2048][16][512]
  const float* Ws  = (const float*)d_in[1];  // [5][1536][512]
  const float* bs  = (const float*)d_in[2];  // [5][1024]
  const float* fcW = (const float*)d_in[3];  // [10][512]
  const float* fcb = (const float*)d_in[4];  // [10]
  float* out = (float*)d_out;

  char* ws = (char*)d_ws;
  const size_t MiB = 1024 * 1024;
  unsigned short* Ub = (unsigned short*)ws;                  // 96 MiB: [M][1536] bf16
  float*          hF = (float*)(ws + 96 * MiB);              // 64 MiB: [M][512] f32
  unsigned short* hB = (unsigned short*)(ws + 160 * MiB);    // 32 MiB: [M][512] bf16
  unsigned short* Wb = (unsigned short*)(ws + 192 * MiB);    // 15.75 MiB: [5][1536][512] bf16
  float*        Fseg = (float*)(ws + 208 * MiB);             // 2 MiB
  float*        Cseg = (float*)(ws + 210 * MiB);             // 2 MiB
  // total 212 MiB <= 256 MiB workspace

  // one-time converts (per call; inputs never mutated)
  cvt_f32_to_bf16<<<(NLAYERS * N3H * HID) / (256 * 8), 256, 0, stream>>>(Ws, Wb);
  cvt_f32_to_bf16<<<(M_ROWS * HID) / (256 * 8), 256, 0, stream>>>(x, hB);

  const float* xin_f32 = x;
  for (int l = 0; l < NLAYERS; ++l) {
    dim3 g(M_ROWS / 128, N3H / 128);
    gemm_mfma<<<g, 256, 0, stream>>>(hB, Wb + (size_t)l * N3H * HID, Ub);
    const float* bias = bs + (size_t)l * 2 * HID;
    int nthr = BATCH * HID * NSEG;  // 524288
    scan_pass1<<<nthr / 256, 256, 0, stream>>>(Ub, bias, Fseg, Cseg);
    scan_mid<<<BATCH * HID / 256, 256, 0, stream>>>(Fseg, Cseg);
    scan_pass3<<<nthr / 256, 256, 0, stream>>>(Ub, xin_f32, bias, Cseg, hF, hB);
    xin_f32 = hF;
  }
  fc_kernel<<<M_ROWS / FCR, 256, 0, stream>>>(hF, fcW, fcb, out);
}

// Round 4
// 780.873 us; speedup vs baseline: 11.3639x; 1.0213x over previous
//
#include <hip/hip_runtime.h>
#include <hip/hip_bf16.h>

#define SEQ 2048
#define BATCH 16
#define HID 512
#define OUT_DIM 10
#define NLAYERS 5
#define M_ROWS (SEQ * BATCH)   // 32768
#define N3H (3 * HID)          // 1536
#define GK HID                 // GEMM K

#define CHUNK 32
#define NSEG (SEQ / CHUNK)     // 64

typedef __attribute__((ext_vector_type(8))) short short8;
typedef __attribute__((ext_vector_type(4))) float f32x4;
typedef __attribute__((ext_vector_type(8))) unsigned short u16x8;

__device__ __forceinline__ unsigned short f2bf(float x) {
  unsigned u = __builtin_bit_cast(unsigned, x);
  u += 0x7fffu + ((u >> 16) & 1u);   // RNE
  return (unsigned short)(u >> 16);
}
__device__ __forceinline__ float bf2f(unsigned short v) {
  return __builtin_bit_cast(float, ((unsigned)v) << 16);
}

// ---------------- f32 -> bf16 bulk convert (8 elems/thread) ----------------
__global__ __launch_bounds__(256) void cvt_f32_to_bf16(const float* __restrict__ in,
                                                       unsigned short* __restrict__ out) {
  size_t i = ((size_t)blockIdx.x * 256 + threadIdx.x) * 8;
  float4 a = *(const float4*)(in + i);
  float4 b = *(const float4*)(in + i + 4);
  u16x8 r;
  r[0] = f2bf(a.x); r[1] = f2bf(a.y); r[2] = f2bf(a.z); r[3] = f2bf(a.w);
  r[4] = f2bf(b.x); r[5] = f2bf(b.y); r[6] = f2bf(b.z); r[7] = f2bf(b.w);
  *(u16x8*)(out + i) = r;
}

// ---------------- bf16 MFMA GEMM: C[m][n] = sum_k A[m][k] * B[n][k] ----------------
// A: [M][512] bf16 row-major; B: [1536][512] bf16 (B^T layout); C: [M][1536] bf16.
// 128x128 tile, BK=32, 256 threads (4 waves, each a 64x64 quadrant).
// LDS tiles XOR-swizzled: logical k-chunk q at row r lives in physical chunk
// q ^ (r&3). Staging keeps the LDS dest linear (global_load_lds requirement)
// and pre-swizzles the GLOBAL source chunk instead (rule: both-sides-or-neither).
__global__ __launch_bounds__(256) void gemm_mfma(const unsigned short* __restrict__ A,
                                                 const unsigned short* __restrict__ B,
                                                 unsigned short* __restrict__ C) {
  __shared__ unsigned short lds[2][8192];  // [buf]: A tile 128x32 @0, B tile @4096
  const int tid = threadIdx.x;
  const int bm = blockIdx.x, bn = blockIdx.y;
  const int lane = tid & 63;
  const int wid = tid >> 6;
  const int wm = (wid >> 1) * 64, wn = (wid & 1) * 64;

  const unsigned short* Ag = A + (size_t)bm * 128 * GK;
  const unsigned short* Bg = B + (size_t)bn * 128 * GK;

  // staging slot s covers LDS row r = s>>2, physical chunk q = s&3.
  // source k-chunk = q ^ (r&3)  (inverse swizzle applied to the source)
  const int s0 = tid, s1 = tid + 256;
  const int r0 = s0 >> 2, c0 = ((s0 & 3) ^ (r0 & 3)) * 8;
  const int r1 = s1 >> 2, c1 = ((s1 & 3) ^ (r1 & 3)) * 8;

  const int fr = lane & 15;         // fragment row (M for A, N for B)
  const int slot = lane >> 4;       // k-chunk slot (8 contiguous k)
  const int sw = slot ^ (fr & 15 & 3);  // swizzled physical chunk (row&3 == fr&3)

  f32x4 acc[4][4];
#pragma unroll
  for (int i = 0; i < 4; ++i)
#pragma unroll
    for (int j = 0; j < 4; ++j) acc[i][j] = (f32x4){0.f, 0.f, 0.f, 0.f};

#define STAGE(buf, k0)                                                                              \
  {                                                                                                 \
    __builtin_amdgcn_global_load_lds(                                                               \
        (const __attribute__((address_space(1))) void*)(Ag + (size_t)r0 * GK + (k0) + c0),          \
        (__attribute__((address_space(3))) void*)&lds[buf][s0 * 8], 16, 0, 0);                      \
    __builtin_amdgcn_global_load_lds(                                                               \
        (const __attribute__((address_space(1))) void*)(Ag + (size_t)r1 * GK + (k0) + c1),          \
        (__attribute__((address_space(3))) void*)&lds[buf][s1 * 8], 16, 0, 0);                      \
    __builtin_amdgcn_global_load_lds(                                                               \
        (const __attribute__((address_space(1))) void*)(Bg + (size_t)r0 * GK + (k0) + c0),          \
        (__attribute__((address_space(3))) void*)&lds[buf][4096 + s0 * 8], 16, 0, 0);               \
    __builtin_amdgcn_global_load_lds(                                                               \
        (const __attribute__((address_space(1))) void*)(Bg + (size_t)r1 * GK + (k0) + c1),          \
        (__attribute__((address_space(3))) void*)&lds[buf][4096 + s1 * 8], 16, 0, 0);               \
  }

  STAGE(0, 0);
  __syncthreads();
  int cur = 0;
#pragma unroll 1
  for (int kt = 0; kt < GK / 32; ++kt) {
    if (kt + 1 < GK / 32) STAGE(cur ^ 1, (kt + 1) * 32);
    short8 af[4], bfr[4];
#pragma unroll
    for (int t = 0; t < 4; ++t) {
      af[t]  = *(const short8*)&lds[cur][(wm + t * 16 + fr) * 32 + sw * 8];
      bfr[t] = *(const short8*)&lds[cur][4096 + (wn + t * 16 + fr) * 32 + sw * 8];
    }
#pragma unroll
    for (int mt = 0; mt < 4; ++mt)
#pragma unroll
      for (int nt = 0; nt < 4; ++nt)
        acc[mt][nt] = __builtin_amdgcn_mfma_f32_16x16x32_bf16(af[mt], bfr[nt], acc[mt][nt], 0, 0, 0);
    if (kt + 1 < GK / 32) {
      __syncthreads();   // drains vmcnt (stage done) + lgkm (reads done)
      cur ^= 1;
    }
  }
#undef STAGE

  // ---- coalesced C-write via LDS transpose (reuse staging LDS: 32 KB) ----
  __syncthreads();  // all waves done reading final tile
  unsigned short* cl = &lds[0][0];  // 128x128 bf16 tile, row-major
  const int er = (lane >> 4) * 4;   // C/D layout: col=lane&15, row=(lane>>4)*4+reg
#pragma unroll
  for (int mt = 0; mt < 4; ++mt)
#pragma unroll
    for (int nt = 0; nt < 4; ++nt) {
      const int row = wm + mt * 16 + er;
      const int col = wn + nt * 16 + fr;
#pragma unroll
      for (int j = 0; j < 4; ++j) cl[(row + j) * 128 + col] = f2bf(acc[mt][nt][j]);
    }
  __syncthreads();
  unsigned short* Cb = C + (size_t)bm * 128 * N3H + bn * 128;
#pragma unroll
  for (int i = 0; i < 8; ++i) {
    int flat = i * 2048 + tid * 8;
    int r = flat >> 7, c = flat & 127;
    *(short8*)(Cb + (size_t)r * N3H + c) = *(const short8*)&cl[flat];
  }
}

// ---------------- Segment-parallel SRU scan ----------------
__global__ __launch_bounds__(256) void scan_pass1(const unsigned short* __restrict__ U,
                                                  const float* __restrict__ bias,
                                                  float* __restrict__ Fseg,
                                                  float* __restrict__ Cseg) {
  int t = blockIdx.x * 256 + threadIdx.x;   // (s, b, h)
  int h = t & (HID - 1);
  int b = (t >> 9) & (BATCH - 1);
  int s = t >> 13;
  const float bfv = bias[h];
  const unsigned short* Up = U + (size_t)(s * CHUNK) * BATCH * N3H + (size_t)b * N3H + h;
  float F = 1.f, c = 0.f;
#pragma unroll 8
  for (int i = 0; i < CHUNK; ++i) {
    float xt = bf2f(Up[0]);
    float zf = bf2f(Up[HID]);
    float f = 1.f / (1.f + __expf(-(zf + bfv)));
    c = f * c + (1.f - f) * xt;
    F *= f;
    Up += BATCH * N3H;
  }
  size_t o = ((size_t)s * BATCH + b) * HID + h;
  Fseg[o] = F;
  Cseg[o] = c;
}

// per chain: serial scan over segment summaries; writes the INCOMING carry
// for each segment in-place into Cseg.
__global__ __launch_bounds__(256) void scan_mid(const float* __restrict__ Fseg,
                                                float* Cseg) {
  int t = blockIdx.x * 256 + threadIdx.x;   // 0..8191
  float c = 0.f;
#pragma unroll 4
  for (int s = 0; s < NSEG; ++s) {
    size_t o = (size_t)s * BATCH * HID + t;
    float F = Fseg[o], Cv = Cseg[o];
    Cseg[o] = c;          // incoming carry for segment s
    c = F * c + Cv;
  }
}

// pass3: apply carry, recompute gates, highway; writes f32 h + bf16 mirror.
// xin/hF may alias (in-place): per element read-then-write by same thread.
__global__ __launch_bounds__(256) void scan_pass3(const unsigned short* __restrict__ U,
                                                  const float* xin,
                                                  const float* __restrict__ bias,
                                                  const float* __restrict__ Cin,
                                                  float* hF,
                                                  unsigned short* __restrict__ hB) {
  int t = blockIdx.x * 256 + threadIdx.x;
  int h = t & (HID - 1);
  int b = (t >> 9) & (BATCH - 1);
  int s = t >> 13;
  const float bfv = bias[h];
  const float brv = bias[HID + h];
  float c = Cin[(size_t)s * BATCH * HID + (b << 9) + h];
  const unsigned short* Up = U + (size_t)(s * CHUNK) * BATCH * N3H + (size_t)b * N3H + h;
  const float* xp = xin + (size_t)(s * CHUNK) * BATCH * HID + (b << 9) + h;
  float* hp = hF + (size_t)(s * CHUNK) * BATCH * HID + (b << 9) + h;
  unsigned short* hbp = hB + (size_t)(s * CHUNK) * BATCH * HID + (b << 9) + h;
#pragma unroll 4
  for (int i = 0; i < CHUNK; ++i) {
    float xt = bf2f(Up[0]);
    float zf = bf2f(Up[HID]);
    float zr = bf2f(Up[2 * HID]);
    float xv = xp[0];
    float f = 1.f / (1.f + __expf(-(zf + bfv)));
    float r = 1.f / (1.f + __expf(-(zr + brv)));
    c = f * c + (1.f - f) * xt;
    float hv = r * c + (1.f - r) * xv;
    hp[0] = hv;
    hbp[0] = f2bf(hv);
    Up += BATCH * N3H;
    xp += BATCH * HID;
    hp += BATCH * HID;
    hbp += BATCH * HID;
  }
}

// ---------------- FC head (f32 H) ----------------
#define FCR 16
__global__ __launch_bounds__(256) void fc_kernel(const float* __restrict__ H,
                                                 const float* __restrict__ W,
                                                 const float* __restrict__ bv,
                                                 float* __restrict__ out) {
  __shared__ float hs[FCR][516];
  __shared__ float ws[OUT_DIM][516];
  const int tid = threadIdx.x;
  const size_t m0 = (size_t)blockIdx.x * FCR;
#pragma unroll
  for (int i = 0; i < 8; ++i) {
    int f = tid + i * 256;
    int row = f >> 7;
    int kq = f & 127;
    float4 v = *(const float4*)(H + (m0 + row) * 512 + kq * 4);
    *(float4*)&hs[row][kq * 4] = v;
  }
#pragma unroll
  for (int i = 0; i < 5; ++i) {
    int f = tid + i * 256;
    int row = f >> 7;
    int kq = f & 127;
    float4 v = *(const float4*)(W + row * 512 + kq * 4);
    *(float4*)&ws[row][kq * 4] = v;
  }
  __syncthreads();
  if (tid < FCR * OUT_DIM) {
    int row = tid / OUT_DIM;
    int o = tid - row * OUT_DIM;
    float acc = bv[o];
#pragma unroll 8
    for (int k = 0; k < 512; ++k) acc += hs[row][k] * ws[o][k];
    out[(m0 + row) * OUT_DIM + o] = acc;
  }
}

extern "C" void kernel_launch(void* const* d_in, const int* in_sizes, int n_in,
                              void* d_out, int out_size, void* d_ws, size_t ws_size,
                              hipStream_t stream) {
  const float* x   = (const float*)d_in[0];  // [2048][16][512]
  const float* Ws  = (const float*)d_in[1];  // [5][1536][512]
  const float* bs  = (const float*)d_in[2];  // [5][1024]
  const float* fcW = (const float*)d_in[3];  // [10][512]
  const float* fcb = (const float*)d_in[4];  // [10]
  float* out = (float*)d_out;

  char* ws = (char*)d_ws;
  const size_t MiB = 1024 * 1024;
  unsigned short* Ub = (unsigned short*)ws;                  // 96 MiB: [M][1536] bf16
  float*          hF = (float*)(ws + 96 * MiB);              // 64 MiB: [M][512] f32
  unsigned short* hB = (unsigned short*)(ws + 160 * MiB);    // 32 MiB: [M][512] bf16
  unsigned short* Wb = (unsigned short*)(ws + 192 * MiB);    // 15.75 MiB: [5][1536][512] bf16
  float*        Fseg = (float*)(ws + 208 * MiB);             // 2 MiB
  float*        Cseg = (float*)(ws + 210 * MiB);             // 2 MiB
  // total 212 MiB <= 256 MiB workspace

  // one-time converts (per call; inputs never mutated)
  cvt_f32_to_bf16<<<(NLAYERS * N3H * HID) / (256 * 8), 256, 0, stream>>>(Ws, Wb);
  cvt_f32_to_bf16<<<(M_ROWS * HID) / (256 * 8), 256, 0, stream>>>(x, hB);

  const float* xin_f32 = x;
  for (int l = 0; l < NLAYERS; ++l) {
    dim3 g(M_ROWS / 128, N3H / 128);
    gemm_mfma<<<g, 256, 0, stream>>>(hB, Wb + (size_t)l * N3H * HID, Ub);
    const float* bias = bs + (size_t)l * 2 * HID;
    int nthr = BATCH * HID * NSEG;  // 524288
    scan_pass1<<<nthr / 256, 256, 0, stream>>>(Ub, bias, Fseg, Cseg);
    scan_mid<<<BATCH * HID / 256, 256, 0, stream>>>(Fseg, Cseg);
    scan_pass3<<<nthr / 256, 256, 0, stream>>>(Ub, xin_f32, bias, Cseg, hF, hB);
    xin_f32 = hF;
  }
  fc_kernel<<<M_ROWS / FCR, 256, 0, stream>>>(hF, fcW, fcb, out);
}

// Round 5
// 654.764 us; speedup vs baseline: 13.5526x; 1.1926x over previous
//
#include <hip/hip_runtime.h>
#include <hip/hip_bf16.h>

#define SEQ 2048
#define BATCH 16
#define HID 512
#define OUT_DIM 10
#define NLAYERS 5
#define M_ROWS (SEQ * BATCH)   // 32768
#define N3H (3 * HID)          // 1536
#define GK HID                 // GEMM K

#define CHUNK 32
#define NSEG (SEQ / CHUNK)     // 64

typedef __attribute__((ext_vector_type(8))) _Float16 f16x8;
typedef __attribute__((ext_vector_type(4))) float f32x4;
typedef __attribute__((ext_vector_type(8))) unsigned short u16x8;

__device__ __forceinline__ unsigned short f2h(float x) {
  return __builtin_bit_cast(unsigned short, (_Float16)x);
}
__device__ __forceinline__ float h2f(unsigned short v) {
  return (float)__builtin_bit_cast(_Float16, v);
}

// ---------------- f32 -> f16 bulk convert (8 elems/thread) ----------------
__global__ __launch_bounds__(256) void cvt_f32_to_f16(const float* __restrict__ in,
                                                      unsigned short* __restrict__ out) {
  size_t i = ((size_t)blockIdx.x * 256 + threadIdx.x) * 8;
  float4 a = *(const float4*)(in + i);
  float4 b = *(const float4*)(in + i + 4);
  u16x8 r;
  r[0] = f2h(a.x); r[1] = f2h(a.y); r[2] = f2h(a.z); r[3] = f2h(a.w);
  r[4] = f2h(b.x); r[5] = f2h(b.y); r[6] = f2h(b.z); r[7] = f2h(b.w);
  *(u16x8*)(out + i) = r;
}

// ---------------- f16 MFMA GEMM: C[m][n] = sum_k A[m][k] * B[n][k] ----------------
// A: [M][512] f16 row-major; B: [1536][512] f16 (B^T layout); C: [M][1536] f16.
// 128x128 tile, BK=32, 256 threads (4 waves, each a 64x64 quadrant).
// 1-D grid with bijective XCD-chunked swizzle: flat = bm*12+bn (bn fastest, so
// a chunk of consecutive flats shares A panels); each XCD gets 384 consecutive
// flats = 32 bm-panels = 4 MiB of A = one L2.
__global__ __launch_bounds__(256) void gemm_mfma(const unsigned short* __restrict__ A,
                                                 const unsigned short* __restrict__ B,
                                                 unsigned short* __restrict__ C) {
  __shared__ unsigned short lds[2][8192];  // [buf]: A tile 128x32 @0, B tile @4096
  const int tid = threadIdx.x;
  // XCD-chunked swizzle (nwg = 3072, divisible by 8 -> bijective)
  const int nwg = (M_ROWS / 128) * (N3H / 128);      // 3072
  const int cpx = nwg / 8;                           // 384
  const int swz = (blockIdx.x % 8) * cpx + blockIdx.x / 8;
  const int bm = swz / (N3H / 128);
  const int bn = swz % (N3H / 128);
  const int lane = tid & 63;
  const int wid = tid >> 6;
  const int wm = (wid >> 1) * 64, wn = (wid & 1) * 64;

  const unsigned short* Ag = A + (size_t)bm * 128 * GK;
  const unsigned short* Bg = B + (size_t)bn * 128 * GK;

  // staging: slot s in [0,512) covers (row = s>>2, 8-elem chunk = s&3)
  const int s0 = tid, s1 = tid + 256;
  const int r0 = s0 >> 2, c0 = (s0 & 3) * 8;
  const int r1 = s1 >> 2, c1 = (s1 & 3) * 8;

  const int fr = lane & 15;         // fragment row (M for A, N for B)
  const int ko = (lane >> 4) * 8;   // fragment k offset (8 contiguous)

  f32x4 acc[4][4];
#pragma unroll
  for (int i = 0; i < 4; ++i)
#pragma unroll
    for (int j = 0; j < 4; ++j) acc[i][j] = (f32x4){0.f, 0.f, 0.f, 0.f};

#define STAGE(buf, k0)                                                                              \
  {                                                                                                 \
    __builtin_amdgcn_global_load_lds(                                                               \
        (const __attribute__((address_space(1))) void*)(Ag + (size_t)r0 * GK + (k0) + c0),          \
        (__attribute__((address_space(3))) void*)&lds[buf][s0 * 8], 16, 0, 0);                      \
    __builtin_amdgcn_global_load_lds(                                                               \
        (const __attribute__((address_space(1))) void*)(Ag + (size_t)r1 * GK + (k0) + c1),          \
        (__attribute__((address_space(3))) void*)&lds[buf][s1 * 8], 16, 0, 0);                      \
    __builtin_amdgcn_global_load_lds(                                                               \
        (const __attribute__((address_space(1))) void*)(Bg + (size_t)r0 * GK + (k0) + c0),          \
        (__attribute__((address_space(3))) void*)&lds[buf][4096 + s0 * 8], 16, 0, 0);               \
    __builtin_amdgcn_global_load_lds(                                                               \
        (const __attribute__((address_space(1))) void*)(Bg + (size_t)r1 * GK + (k0) + c1),          \
        (__attribute__((address_space(3))) void*)&lds[buf][4096 + s1 * 8], 16, 0, 0);               \
  }

  STAGE(0, 0);
  __syncthreads();
  int cur = 0;
#pragma unroll 1
  for (int kt = 0; kt < GK / 32; ++kt) {
    if (kt + 1 < GK / 32) STAGE(cur ^ 1, (kt + 1) * 32);
    f16x8 af[4], bfr[4];
#pragma unroll
    for (int t = 0; t < 4; ++t) {
      af[t]  = *(const f16x8*)&lds[cur][(wm + t * 16 + fr) * 32 + ko];
      bfr[t] = *(const f16x8*)&lds[cur][4096 + (wn + t * 16 + fr) * 32 + ko];
    }
#pragma unroll
    for (int mt = 0; mt < 4; ++mt)
#pragma unroll
      for (int nt = 0; nt < 4; ++nt)
        acc[mt][nt] = __builtin_amdgcn_mfma_f32_16x16x32_f16(af[mt], bfr[nt], acc[mt][nt], 0, 0, 0);
    if (kt + 1 < GK / 32) {
      __syncthreads();
      cur ^= 1;
    }
  }
#undef STAGE

  // ---- coalesced C-write via LDS transpose (reuse staging LDS: 32 KB) ----
  __syncthreads();  // all waves done reading final tile
  unsigned short* cl = &lds[0][0];  // 128x128 f16 tile, row-major
  const int er = (lane >> 4) * 4;   // C/D layout: col=lane&15, row=(lane>>4)*4+reg
#pragma unroll
  for (int mt = 0; mt < 4; ++mt)
#pragma unroll
    for (int nt = 0; nt < 4; ++nt) {
      const int row = wm + mt * 16 + er;
      const int col = wn + nt * 16 + fr;
#pragma unroll
      for (int j = 0; j < 4; ++j) cl[(row + j) * 128 + col] = f2h(acc[mt][nt][j]);
    }
  __syncthreads();
  unsigned short* Cb = C + (size_t)bm * 128 * N3H + bn * 128;
#pragma unroll
  for (int i = 0; i < 8; ++i) {
    int flat = i * 2048 + tid * 8;
    int r = flat >> 7, c = flat & 127;
    *(u16x8*)(Cb + (size_t)r * N3H + c) = *(const u16x8*)&cl[flat];
  }
}

// ---------------- Segment-parallel SRU scan (f16 data, f32 math) ----------------
__global__ __launch_bounds__(256) void scan_pass1(const unsigned short* __restrict__ U,
                                                  const float* __restrict__ bias,
                                                  float* __restrict__ Fseg,
                                                  float* __restrict__ Cseg) {
  int t = blockIdx.x * 256 + threadIdx.x;   // (s, b, h)
  int h = t & (HID - 1);
  int b = (t >> 9) & (BATCH - 1);
  int s = t >> 13;
  const float bfv = bias[h];
  const unsigned short* Up = U + (size_t)(s * CHUNK) * BATCH * N3H + (size_t)b * N3H + h;
  float F = 1.f, c = 0.f;
#pragma unroll 8
  for (int i = 0; i < CHUNK; ++i) {
    float xt = h2f(Up[0]);
    float zf = h2f(Up[HID]);
    float f = 1.f / (1.f + __expf(-(zf + bfv)));
    c = f * c + (1.f - f) * xt;
    F *= f;
    Up += BATCH * N3H;
  }
  size_t o = ((size_t)s * BATCH + b) * HID + h;
  Fseg[o] = F;
  Cseg[o] = c;
}

// per chain: serial scan over segment summaries; writes the INCOMING carry
// for each segment in-place into Cseg.
__global__ __launch_bounds__(256) void scan_mid(const float* __restrict__ Fseg,
                                                float* Cseg) {
  int t = blockIdx.x * 256 + threadIdx.x;   // 0..8191
  float c = 0.f;
#pragma unroll 4
  for (int s = 0; s < NSEG; ++s) {
    size_t o = (size_t)s * BATCH * HID + t;
    float F = Fseg[o], Cv = Cseg[o];
    Cseg[o] = c;          // incoming carry for segment s
    c = F * c + Cv;
  }
}

// pass3: apply carry, recompute gates, highway; in-place on the f16 h buffer
// (each element is read then written by the same thread in the same iter).
__global__ __launch_bounds__(256) void scan_pass3(const unsigned short* __restrict__ U,
                                                  const float* __restrict__ bias,
                                                  const float* __restrict__ Cin,
                                                  unsigned short* hb) {
  int t = blockIdx.x * 256 + threadIdx.x;
  int h = t & (HID - 1);
  int b = (t >> 9) & (BATCH - 1);
  int s = t >> 13;
  const float bfv = bias[h];
  const float brv = bias[HID + h];
  float c = Cin[(size_t)s * BATCH * HID + (b << 9) + h];
  const unsigned short* Up = U + (size_t)(s * CHUNK) * BATCH * N3H + (size_t)b * N3H + h;
  unsigned short* hp = hb + (size_t)(s * CHUNK) * BATCH * HID + (b << 9) + h;
#pragma unroll 4
  for (int i = 0; i < CHUNK; ++i) {
    float xt = h2f(Up[0]);
    float zf = h2f(Up[HID]);
    float zr = h2f(Up[2 * HID]);
    float xv = h2f(hp[0]);
    float f = 1.f / (1.f + __expf(-(zf + bfv)));
    float r = 1.f / (1.f + __expf(-(zr + brv)));
    c = f * c + (1.f - f) * xt;
    hp[0] = f2h(r * c + (1.f - r) * xv);
    Up += BATCH * N3H;
    hp += BATCH * HID;
  }
}

// ---------------- FC head (f16 H, f32 math) ----------------
#define FCR 16
__global__ __launch_bounds__(256) void fc_kernel(const unsigned short* __restrict__ H,
                                                 const float* __restrict__ W,
                                                 const float* __restrict__ bv,
                                                 float* __restrict__ out) {
  __shared__ float hs[FCR][516];
  __shared__ float ws[OUT_DIM][516];
  const int tid = threadIdx.x;
  const size_t m0 = (size_t)blockIdx.x * FCR;
  // load 16 rows of H (f16): 16*512 = 8192 elems -> 8-elem vectors, 4/thread
#pragma unroll
  for (int i = 0; i < 4; ++i) {
    int f = tid + i * 256;
    int row = f >> 6;     // 0..15
    int kq = f & 63;      // 8-elem group
    u16x8 v = *(const u16x8*)(H + (m0 + row) * 512 + kq * 8);
#pragma unroll
    for (int j = 0; j < 8; ++j) hs[row][kq * 8 + j] = h2f(v[j]);
  }
#pragma unroll
  for (int i = 0; i < 5; ++i) {
    int f = tid + i * 256;
    int row = f >> 7;     // 0..9
    int kq = f & 127;
    float4 v = *(const float4*)(W + row * 512 + kq * 4);
    *(float4*)&ws[row][kq * 4] = v;
  }
  __syncthreads();
  if (tid < FCR * OUT_DIM) {
    int row = tid / OUT_DIM;
    int o = tid - row * OUT_DIM;
    float acc = bv[o];
#pragma unroll 8
    for (int k = 0; k < 512; ++k) acc += hs[row][k] * ws[o][k];
    out[(m0 + row) * OUT_DIM + o] = acc;
  }
}

extern "C" void kernel_launch(void* const* d_in, const int* in_sizes, int n_in,
                              void* d_out, int out_size, void* d_ws, size_t ws_size,
                              hipStream_t stream) {
  const float* x   = (const float*)d_in[0];  // [2048][16][512]
  const float* Ws  = (const float*)d_in[1];  // [5][1536][512]
  const float* bs  = (const float*)d_in[2];  // [5][1024]
  const float* fcW = (const float*)d_in[3];  // [10][512]
  const float* fcb = (const float*)d_in[4];  // [10]
  float* out = (float*)d_out;

  char* ws = (char*)d_ws;
  const size_t MiB = 1024 * 1024;
  unsigned short* Ub = (unsigned short*)ws;                  // 96 MiB: [M][1536] f16
  unsigned short* hb = (unsigned short*)(ws + 96 * MiB);     // 32 MiB: [M][512] f16
  unsigned short* Wh = (unsigned short*)(ws + 128 * MiB);    // 7.5 MiB: [5][1536][512] f16
  float*        Fseg = (float*)(ws + 136 * MiB);             // 2 MiB
  float*        Cseg = (float*)(ws + 138 * MiB);             // 2 MiB
  // total 140 MiB <= 256 MiB workspace

  // one-time converts (per call; inputs never mutated)
  cvt_f32_to_f16<<<(NLAYERS * N3H * HID) / (256 * 8), 256, 0, stream>>>(Ws, Wh);
  cvt_f32_to_f16<<<(M_ROWS * HID) / (256 * 8), 256, 0, stream>>>(x, hb);

  for (int l = 0; l < NLAYERS; ++l) {
    gemm_mfma<<<(M_ROWS / 128) * (N3H / 128), 256, 0, stream>>>(
        hb, Wh + (size_t)l * N3H * HID, Ub);
    const float* bias = bs + (size_t)l * 2 * HID;
    int nthr = BATCH * HID * NSEG;  // 524288
    scan_pass1<<<nthr / 256, 256, 0, stream>>>(Ub, bias, Fseg, Cseg);
    scan_mid<<<BATCH * HID / 256, 256, 0, stream>>>(Fseg, Cseg);
    scan_pass3<<<nthr / 256, 256, 0, stream>>>(Ub, bias, Cseg, hb);
  }
  fc_kernel<<<M_ROWS / FCR, 256, 0, stream>>>(hb, fcW, fcb, out);
}